// Round 9
// baseline (107.359 us; speedup 1.0000x reference)
//
#include <hip/hip_runtime.h>
#include <hip/hip_bf16.h>

// Fully fused QuanvolutionHybridClassifier forward (round 7 design,
// third submission — rounds 7-8 failed on GPU acquisition, no counters).
//
// Circuit collapse (verified): with a_w = d_w + q_w,
//   z0 = cos a0
//   z1 = cos q4 * cos a0 * cos a1 - sin q4 * sin a1
//   z2 = z1 * cos a2
//   z3 = cos a2 * cos a3
//
// Round-7 restructure (rounds 2-6 micro-fixes only moved 44->38 us):
//  - SPB=8, grid 1024 -> 4 blocks/CU = resident capacity: whole grid
//    co-resident from launch, no straggler tail rounds.
//  - step 2 eliminated: quantum features computed on the fly in step 3
//    (K-half h=1 lanes map 1:1 to patches); LDS halves to flat-only,
//    one barrier and ~1200 DS-ops/block removed.
//  - wave = (K-half, pair-group) serves 4 samples: lin_w float4 loads
//    shared across 4 accumulator sets (2x FMA per loaded byte vs r6).
//  - step-1 LDS writes as float2.

#define SPB 8          // samples per block
#define THREADS 256
#define NCLS 10
#define FEAT 1568      // 784 flat + 784 quantum
#define HALF 784

__global__ __launch_bounds__(THREADS, 4)
void quanv_fused_kernel(const float* __restrict__ x,        // [B,1,28,28]
                        const float* __restrict__ conv_w,   // [4,1,2,2]
                        const float* __restrict__ conv_b,   // [4]
                        const float* __restrict__ q_params, // [5]
                        const float* __restrict__ lin_w,    // [10,1568]
                        const float* __restrict__ lin_b,    // [10]
                        float* __restrict__ out)            // [B,10]
{
    __shared__ __attribute__((aligned(16))) float flat[SPB][HALF]; // 25088 B
    __shared__ float part[SPB][2][12];                             // 768 B

    const int tid = threadIdx.x;
    const int n0  = blockIdx.x * SPB;

    // ---- uniform small params ----
    float W[4][4], Bc[4];
    #pragma unroll
    for (int c = 0; c < 4; ++c) {
        #pragma unroll
        for (int k = 0; k < 4; ++k) W[c][k] = conv_w[c * 4 + k];
        Bc[c] = conv_b[c];
    }
    const float qp0 = q_params[0], qp1 = q_params[1];
    const float qp2 = q_params[2], qp3 = q_params[3];
    const float q4  = q_params[4];
    const float cq4 = __cosf(q4), sq4 = __sinf(q4);

    // ---- Step 1: conv (2x2, stride 2, 4 ch) -> flat[s][0..783]
    // flat layout: c*196 + h*14 + w. Two adjacent outputs per item via two
    // float4 row loads; LDS stores as float2 (r even).
    for (int p = tid; p < SPB * 98; p += THREADS) {
        const int s = p / 98, t = p % 98;
        const int h = t / 7, wp = t % 7;
        const float* xp = x + (size_t)(n0 + s) * 784 + 56 * h + 4 * wp;
        const float4 r0 = *reinterpret_cast<const float4*>(xp);
        const float4 r1 = *reinterpret_cast<const float4*>(xp + 28);
        const int r = h * 14 + 2 * wp;
        #pragma unroll
        for (int c = 0; c < 4; ++c) {
            const float v0 =
                fmaf(r0.x, W[c][0], fmaf(r0.y, W[c][1],
                fmaf(r1.x, W[c][2], fmaf(r1.y, W[c][3], Bc[c]))));
            const float v1 =
                fmaf(r0.z, W[c][0], fmaf(r0.w, W[c][1],
                fmaf(r1.z, W[c][2], fmaf(r1.w, W[c][3], Bc[c]))));
            *reinterpret_cast<float2*>(&flat[s][c * 196 + r]) =
                make_float2(v0, v1);
        }
    }
    __syncthreads();

    // ---- Step 3 (step 2 fused in): linear [1568]x[10] + log_softmax.
    // Wave w: K-half hh = w&1, pair-group pb = w>>1.
    // Samples served: {2pb, 2pb+1, 2pb+4, 2pb+5} (4 acc sets, shared w4).
    const int wave = tid >> 6, lane = tid & 63;
    const int hh = wave & 1, pb = wave >> 1;
    const int sm0 = 2 * pb, sm1 = sm0 + 1, sm2 = sm0 + 4, sm3 = sm0 + 5;
    const int kbase = hh * HALF;

    float acc[4][NCLS];
    #pragma unroll
    for (int m = 0; m < 4; ++m)
        #pragma unroll
        for (int c = 0; c < NCLS; ++c) acc[m][c] = 0.f;

    // 3 strips of 256 floats: [kbase, kbase+768)
    #pragma unroll
    for (int kb = 0; kb < 3; ++kb) {
        const int k = kbase + kb * 256 + lane * 4;
        float4 v[4];
        if (hh == 0) {
            const int kk = kb * 256 + lane * 4;  // < 768
            v[0] = *reinterpret_cast<const float4*>(&flat[sm0][kk]);
            v[1] = *reinterpret_cast<const float4*>(&flat[sm1][kk]);
            v[2] = *reinterpret_cast<const float4*>(&flat[sm2][kk]);
            v[3] = *reinterpret_cast<const float4*>(&flat[sm3][kk]);
        } else {
            const int r = kb * 64 + lane;        // patch id, 0..191
            const int i = r / 14, j = r - 14 * i;
            const int f0 = 56 * i + 2 * j;
            const int sms[4] = {sm0, sm1, sm2, sm3};
            #pragma unroll
            for (int m = 0; m < 4; ++m) {
                const float2 d01 = *reinterpret_cast<const float2*>(&flat[sms[m]][f0]);
                const float2 d23 = *reinterpret_cast<const float2*>(&flat[sms[m]][f0 + 28]);
                const float a0 = d01.x + qp0, a1 = d01.y + qp1;
                const float a2 = d23.x + qp2, a3 = d23.y + qp3;
                const float c0 = __cosf(a0);
                const float c1 = __cosf(a1), s1 = __sinf(a1);
                const float c2 = __cosf(a2), c3 = __cosf(a3);
                const float z1 = cq4 * c0 * c1 - sq4 * s1;
                v[m] = make_float4(c0, z1, z1 * c2, c2 * c3);
            }
        }
        #pragma unroll
        for (int c = 0; c < NCLS; ++c) {
            const float4 w4 = *reinterpret_cast<const float4*>(&lin_w[c * FEAT + k]);
            #pragma unroll
            for (int m = 0; m < 4; ++m) {
                acc[m][c] = fmaf(v[m].x, w4.x, fmaf(v[m].y, w4.y,
                            fmaf(v[m].z, w4.z, fmaf(v[m].w, w4.w, acc[m][c]))));
            }
        }
    }

    // tail [kbase+768, kbase+784): 16 scalars, lanes 0..15
    if (lane < 16) {
        const int k = kbase + 768 + lane;
        float vv[4];
        if (hh == 0) {
            const int kk = 768 + lane;
            vv[0] = flat[sm0][kk]; vv[1] = flat[sm1][kk];
            vv[2] = flat[sm2][kk]; vv[3] = flat[sm3][kk];
        } else {
            const int r = 192 + (lane >> 2);     // 192..195
            const int e = lane & 3;
            const int i = r / 14, j = r - 14 * i;
            const int f0 = 56 * i + 2 * j;
            const int sms[4] = {sm0, sm1, sm2, sm3};
            #pragma unroll
            for (int m = 0; m < 4; ++m) {
                const float2 d01 = *reinterpret_cast<const float2*>(&flat[sms[m]][f0]);
                const float2 d23 = *reinterpret_cast<const float2*>(&flat[sms[m]][f0 + 28]);
                const float a0 = d01.x + qp0, a1 = d01.y + qp1;
                const float a2 = d23.x + qp2, a3 = d23.y + qp3;
                const float c0 = __cosf(a0);
                const float c1 = __cosf(a1), s1 = __sinf(a1);
                const float c2 = __cosf(a2), c3 = __cosf(a3);
                const float z1 = cq4 * c0 * c1 - sq4 * s1;
                const float z2 = z1 * c2, z3 = c2 * c3;
                vv[m] = (e == 0) ? c0 : ((e == 1) ? z1 : ((e == 2) ? z2 : z3));
            }
        }
        #pragma unroll
        for (int c = 0; c < NCLS; ++c) {
            const float w = lin_w[c * FEAT + k];
            #pragma unroll
            for (int m = 0; m < 4; ++m) acc[m][c] = fmaf(vv[m], w, acc[m][c]);
        }
    }

    // butterfly reduce across the 64-lane wave (40 values)
    #pragma unroll
    for (int msk = 1; msk < 64; msk <<= 1) {
        #pragma unroll
        for (int m = 0; m < 4; ++m)
            #pragma unroll
            for (int c = 0; c < NCLS; ++c)
                acc[m][c] += __shfl_xor(acc[m][c], msk, 64);
    }

    if (lane == 0) {
        const int sms[4] = {sm0, sm1, sm2, sm3};
        #pragma unroll
        for (int m = 0; m < 4; ++m)
            #pragma unroll
            for (int c = 0; c < NCLS; ++c)
                part[sms[m]][hh][c] = acc[m][c];
    }
    __syncthreads();

    // ---- Epilogue: one thread per sample combines halves + log_softmax
    if (tid < SPB) {
        const int s = tid;
        float lg[NCLS], mx = -1e30f;
        #pragma unroll
        for (int c = 0; c < NCLS; ++c) {
            lg[c] = part[s][0][c] + part[s][1][c] + lin_b[c];
            mx = fmaxf(mx, lg[c]);
        }
        float sum = 0.f;
        #pragma unroll
        for (int c = 0; c < NCLS; ++c) sum += __expf(lg[c] - mx);
        const float lse = mx + __logf(sum);
        float* o = out + (size_t)(n0 + s) * NCLS;
        #pragma unroll
        for (int c = 0; c < NCLS; ++c) o[c] = lg[c] - lse;
    }
}

extern "C" void kernel_launch(void* const* d_in, const int* in_sizes, int n_in,
                              void* d_out, int out_size, void* d_ws, size_t ws_size,
                              hipStream_t stream) {
    const float* x        = (const float*)d_in[0];
    const float* conv_w   = (const float*)d_in[1];
    const float* conv_b   = (const float*)d_in[2];
    const float* q_params = (const float*)d_in[3];
    const float* lin_w    = (const float*)d_in[4];
    const float* lin_b    = (const float*)d_in[5];
    float* out = (float*)d_out;

    const int B = in_sizes[0] / 784;   // 8192
    const int nblocks = B / SPB;       // 1024

    quanv_fused_kernel<<<nblocks, THREADS, 0, stream>>>(
        x, conv_w, conv_b, q_params, lin_w, lin_b, out);
}

// Round 10
// 93.687 us; speedup vs baseline: 1.1459x; 1.1459x over previous
//
#include <hip/hip_runtime.h>
#include <hip/hip_bf16.h>

// Fully fused QuanvolutionHybridClassifier forward (round 10).
//
// Circuit collapse (verified): with a_w = d_w + q_w,
//   z0 = cos a0
//   z1 = cos q4 * cos a0 * cos a1 - sin q4 * sin a1
//   z2 = z1 * cos a2
//   z3 = cos a2 * cos a3
//
// Round-10: revert to round-6 structure (best measured, kernel ~38us;
// round-7 restructure regressed to ~44us). ONE change: the plain
// 6-stage butterfly over 20 accumulators (120 ds_swizzle + 120 adds
// per thread, ~9us of LDS-pipe time device-wide) is replaced with a
// packed multi-value reduction: stage1 halves values 20->10, stage2
// 10->5, then plain butterfly on 5 (xor 4,8,16,32). 35 shuffles vs 120.
// Final sums land on lanes 0..3 which write part[] directly.

#define SPB 4          // samples per block
#define THREADS 256
#define NCLS 10
#define FEAT 1568      // 784 flat + 784 quantum

__global__ __launch_bounds__(THREADS, 6)
void quanv_fused_kernel(const float* __restrict__ x,        // [B,1,28,28]
                        const float* __restrict__ conv_w,   // [4,1,2,2]
                        const float* __restrict__ conv_b,   // [4]
                        const float* __restrict__ q_params, // [5]
                        const float* __restrict__ lin_w,    // [10,1568]
                        const float* __restrict__ lin_b,    // [10]
                        float* __restrict__ out)            // [B,10]
{
    __shared__ float comb[SPB][FEAT];
    __shared__ float part[SPB][2][12];   // [sample][K-half][class(+pad)]

    const int tid = threadIdx.x;
    const int n0  = blockIdx.x * SPB;

    // ---- uniform small params (L1-broadcast loads) ----
    float W[4][4], Bc[4];
    #pragma unroll
    for (int c = 0; c < 4; ++c) {
        #pragma unroll
        for (int k = 0; k < 4; ++k) W[c][k] = conv_w[c * 4 + k];
        Bc[c] = conv_b[c];
    }
    const float qp0 = q_params[0], qp1 = q_params[1];
    const float qp2 = q_params[2], qp3 = q_params[3];
    const float q4  = q_params[4];
    const float cq4 = __cosf(q4), sq4 = __sinf(q4);

    // ---- Step 1: conv (2x2, stride 2, 4 ch) -> flat region comb[s][0..783]
    for (int p = tid; p < SPB * 14 * 7; p += THREADS) {
        const int s = p / 98, t = p % 98;
        const int h = t / 7, wp = t % 7;
        const float* xp = x + (size_t)(n0 + s) * 784 + 56 * h + 4 * wp;
        const float4 r0 = *reinterpret_cast<const float4*>(xp);
        const float4 r1 = *reinterpret_cast<const float4*>(xp + 28);
        const int r = h * 14 + 2 * wp;
        #pragma unroll
        for (int c = 0; c < 4; ++c) {
            comb[s][c * 196 + r] =
                fmaf(r0.x, W[c][0], fmaf(r0.y, W[c][1],
                fmaf(r1.x, W[c][2], fmaf(r1.y, W[c][3], Bc[c]))));
            comb[s][c * 196 + r + 1] =
                fmaf(r0.z, W[c][0], fmaf(r0.w, W[c][1],
                fmaf(r1.z, W[c][2], fmaf(r1.w, W[c][3], Bc[c]))));
        }
    }
    __syncthreads();

    // ---- Step 2: quantum features on 2x2 patches of the 28x28 view of flat
    for (int p = tid; p < SPB * 196; p += THREADS) {
        const int s = p / 196, r = p % 196;
        const int i = r / 14, j = r % 14;
        const int base = 56 * i + 2 * j;
        const float2 d01 = *reinterpret_cast<const float2*>(&comb[s][base]);
        const float2 d23 = *reinterpret_cast<const float2*>(&comb[s][base + 28]);
        const float a0 = d01.x + qp0, a1 = d01.y + qp1;
        const float a2 = d23.x + qp2, a3 = d23.y + qp3;
        const float c0 = __cosf(a0);
        const float c1 = __cosf(a1), s1 = __sinf(a1);
        const float c2 = __cosf(a2), c3 = __cosf(a3);
        const float z0 = c0;
        const float z1 = cq4 * c0 * c1 - sq4 * s1;
        const float z2 = z1 * c2;
        const float z3 = c2 * c3;
        *reinterpret_cast<float4*>(&comb[s][784 + r * 4]) =
            make_float4(z0, z1, z2, z3);
    }
    __syncthreads();

    // ---- Step 3: linear [1568]x[10] + log_softmax.
    // Wave w = (pair p, K-half h): samples {2p, 2p+1}, K in [784h, 784h+784).
    const int wave = tid >> 6, lane = tid & 63;
    const int pr = wave & 1;
    const int h  = wave >> 1;
    const int s0 = 2 * pr, s1 = s0 + 1;
    const int kbase = h * 784;

    float acc0[NCLS], acc1[NCLS];
    #pragma unroll
    for (int c = 0; c < NCLS; ++c) { acc0[c] = 0.f; acc1[c] = 0.f; }

    // 3 full float4 strips of 256 floats: covers [kbase, kbase+768)
    #pragma unroll
    for (int kb = 0; kb < 3; ++kb) {
        const int k = kbase + kb * 256 + lane * 4;
        const float4 v0 = *reinterpret_cast<const float4*>(&comb[s0][k]);
        const float4 v1 = *reinterpret_cast<const float4*>(&comb[s1][k]);
        #pragma unroll
        for (int c = 0; c < NCLS; ++c) {
            const float4 w4 = *reinterpret_cast<const float4*>(&lin_w[c * FEAT + k]);
            acc0[c] = fmaf(v0.x, w4.x, fmaf(v0.y, w4.y,
                      fmaf(v0.z, w4.z, fmaf(v0.w, w4.w, acc0[c]))));
            acc1[c] = fmaf(v1.x, w4.x, fmaf(v1.y, w4.y,
                      fmaf(v1.z, w4.z, fmaf(v1.w, w4.w, acc1[c]))));
        }
    }
    // tail [kbase+768, kbase+784): 16 scalars, lanes 0..15
    if (lane < 16) {
        const int k = kbase + 768 + lane;
        const float v0 = comb[s0][k];
        const float v1 = comb[s1][k];
        #pragma unroll
        for (int c = 0; c < NCLS; ++c) {
            const float w = lin_w[c * FEAT + k];
            acc0[c] = fmaf(v0, w, acc0[c]);
            acc1[c] = fmaf(v1, w, acc1[c]);
        }
    }

    // ---- Packed multi-value wave reduction: 20 partials -> 5 per lane.
    // Value layout: v[c] = acc0[c] (c<10), v[10+c] = acc1[c].
    // Stage 1 (xor 1): 20 -> 10. Low lane keeps acc0, high keeps acc1;
    // each sends the half it gives away.
    float w10[10];
    {
        const bool hi = (lane & 1) != 0;
        #pragma unroll
        for (int i = 0; i < 10; ++i) {
            const float t = hi ? acc0[i] : acc1[i];        // given-away half
            const float r = __shfl_xor(t, 1, 64);
            w10[i] = (hi ? acc1[i] : acc0[i]) + r;
        }
    }
    // Stage 2 (xor 2): 10 -> 5. Low keeps w10[0..4], high keeps w10[5..9].
    float w5[5];
    {
        const bool hi2 = (lane & 2) != 0;
        #pragma unroll
        for (int i = 0; i < 5; ++i) {
            const float t = hi2 ? w10[i] : w10[5 + i];
            const float r = __shfl_xor(t, 2, 64);
            w5[i] = (hi2 ? w10[5 + i] : w10[i]) + r;
        }
    }
    // Stages 3-6: plain butterfly on 5 values (xor 4, 8, 16, 32).
    #pragma unroll
    for (int m = 4; m < 64; m <<= 1) {
        #pragma unroll
        for (int i = 0; i < 5; ++i)
            w5[i] += __shfl_xor(w5[i], m, 64);
    }
    // Lane q = lane&3 holds complete sums:
    //   q==0: acc0[0..4]  q==1: acc1[0..4]  q==2: acc0[5..9]  q==3: acc1[5..9]
    if (lane < 4) {
        const int ss  = (lane & 1) ? s1 : s0;
        const int co  = (lane & 2) ? 5 : 0;
        #pragma unroll
        for (int i = 0; i < 5; ++i)
            part[ss][h][co + i] = w5[i];
    }
    __syncthreads();

    // ---- Epilogue: one thread per sample combines K-halves + log_softmax
    if (tid < SPB) {
        const int s = tid;
        float lg[NCLS], mx = -1e30f;
        #pragma unroll
        for (int c = 0; c < NCLS; ++c) {
            lg[c] = part[s][0][c] + part[s][1][c] + lin_b[c];
            mx = fmaxf(mx, lg[c]);
        }
        float sum = 0.f;
        #pragma unroll
        for (int c = 0; c < NCLS; ++c) sum += __expf(lg[c] - mx);
        const float lse = mx + __logf(sum);
        float* o = out + (size_t)(n0 + s) * NCLS;
        #pragma unroll
        for (int c = 0; c < NCLS; ++c) o[c] = lg[c] - lse;
    }
}

extern "C" void kernel_launch(void* const* d_in, const int* in_sizes, int n_in,
                              void* d_out, int out_size, void* d_ws, size_t ws_size,
                              hipStream_t stream) {
    const float* x        = (const float*)d_in[0];
    const float* conv_w   = (const float*)d_in[1];
    const float* conv_b   = (const float*)d_in[2];
    const float* q_params = (const float*)d_in[3];
    const float* lin_w    = (const float*)d_in[4];
    const float* lin_b    = (const float*)d_in[5];
    float* out = (float*)d_out;

    const int B = in_sizes[0] / 784;   // 8192
    const int nblocks = B / SPB;       // 2048

    quanv_fused_kernel<<<nblocks, THREADS, 0, stream>>>(
        x, conv_w, conv_b, q_params, lin_w, lin_b, out);
}